// Round 5
// baseline (274.988 us; speedup 1.0000x reference)
//
#include <hip/hip_runtime.h>
#include <hip/hip_bf16.h>

using short8   = __attribute__((ext_vector_type(8))) short;
using floatx4  = __attribute__((ext_vector_type(4))) float;
using floatx16 = __attribute__((ext_vector_type(16))) float;

#define KDIM 768
#define QSCALE 0.18033688011112042f   // 0.125 * log2(e)
#define N1 (8192 * 768)
#define N2 (2304 * 768)
#define N3 (768 * 768)

__device__ __forceinline__ short f2bf(float f) {
    union { float f; unsigned u; } v; v.f = f;
    unsigned r = v.u + 0x7fffu + ((v.u >> 16) & 1u);
    return (short)(r >> 16);
}

__device__ __forceinline__ unsigned pack2bf(float a, float b) {
    __hip_bfloat162 h = __float22bfloat162_rn(float2{a, b});
    union { __hip_bfloat162 h; unsigned u; } c; c.h = h;
    return c.u;
}

__device__ __forceinline__ float fast_exp2(float x) {
#if __has_builtin(__builtin_amdgcn_exp2f)
    return __builtin_amdgcn_exp2f(x);
#else
    return exp2f(x);
#endif
}

__device__ __forceinline__ void async16(const void* g, void* l) {
    __builtin_amdgcn_global_load_lds((const __attribute__((address_space(1))) void*)g,
                                     (__attribute__((address_space(3))) void*)l, 16, 0, 0);
}

// ---------------- fused fp32 -> bf16 convert for all three inputs ----------------
__global__ void cvt_all(const float* __restrict__ a, const float* __restrict__ b,
                        const float* __restrict__ c, short* __restrict__ oa,
                        short* __restrict__ ob, short* __restrict__ oc) {
    int i = (blockIdx.x * blockDim.x + threadIdx.x) * 4;
    const float* src; short* dst;
    if (i < N1)            { src = a + i;            dst = oa + i; }
    else if (i < N1 + N2)  { src = b + (i - N1);     dst = ob + (i - N1); }
    else if (i < N1+N2+N3) { src = c + (i - N1 - N2); dst = oc + (i - N1 - N2); }
    else return;
    float4 v = *(const float4*)src;
    short4 o;
    o.x = f2bf(v.x); o.y = f2bf(v.y); o.z = f2bf(v.z); o.w = f2bf(v.w);
    *(short4*)dst = o;
}

// ---------------- QKV GEMM: C[8192,2304] = X @ W^T, scatter to Q/K/V [bh][s][64] ----------------
__global__ __launch_bounds__(256) void gemm_qkv(
    const short* __restrict__ X, const short* __restrict__ W,
    const float* __restrict__ bias,
    short* __restrict__ Qb, short* __restrict__ Kb, short* __restrict__ Vb)
{
    __shared__ short As[128 * 32];
    __shared__ short Bs[128 * 32];
    int tid = threadIdx.x;
    int w = tid >> 6, l = tid & 63;
    int lane16 = l & 15, quad = l >> 4;
    int wm = w & 1, wn = w >> 1;
    int m0 = blockIdx.y * 128, n0 = blockIdx.x * 128;

    floatx4 acc[4][4] = {};

    int srow = w * 32 + (l >> 2);
    int scol = (l & 3) * 8;
    const short* Xg = X + (size_t)(m0 + srow) * KDIM + scol;
    const short* Wg = W + (size_t)(n0 + srow) * KDIM + scol;
    short* AsW = As + (w * 32) * 32;
    short* BsW = Bs + (w * 32) * 32;

    for (int kb = 0; kb < KDIM; kb += 32) {
        __syncthreads();
        async16(Xg + kb,              AsW);
        async16(Xg + kb + 16 * KDIM,  AsW + 16 * 32);
        async16(Wg + kb,              BsW);
        async16(Wg + kb + 16 * KDIM,  BsW + 16 * 32);
        __syncthreads();
        short8 a[4], b[4];
#pragma unroll
        for (int mt = 0; mt < 4; mt++) a[mt] = *(const short8*)(As + (wm * 64 + mt * 16 + lane16) * 32 + quad * 8);
#pragma unroll
        for (int nt = 0; nt < 4; nt++) b[nt] = *(const short8*)(Bs + (wn * 64 + nt * 16 + lane16) * 32 + quad * 8);
#pragma unroll
        for (int mt = 0; mt < 4; mt++)
#pragma unroll
            for (int nt = 0; nt < 4; nt++)
                acc[mt][nt] = __builtin_amdgcn_mfma_f32_16x16x32_bf16(a[mt], b[nt], acc[mt][nt], 0, 0, 0);
    }

#pragma unroll
    for (int mt = 0; mt < 4; mt++) {
        int row = m0 + wm * 64 + mt * 16 + quad * 4;
#pragma unroll
        for (int nt = 0; nt < 4; nt++) {
            int col = n0 + wn * 64 + nt * 16 + lane16;
            int qkv = (col >= 1536) ? 2 : ((col >= 768) ? 1 : 0);
            int rem = col - qkv * 768;
            int h = rem >> 6, e = rem & 63;
            short* dst = (qkv == 0) ? Qb : ((qkv == 1) ? Kb : Vb);
            float sc = (qkv == 0) ? (float)QSCALE : 1.0f;
            float bv = bias[col];
#pragma unroll
            for (int r = 0; r < 4; r++) {
                int i  = row + r;
                int b_ = i >> 11, s_ = i & 2047;
                dst[(((size_t)(b_ * 12 + h)) * 2048 + s_) * 64 + e] = f2bf((acc[mt][nt][r] + bv) * sc);
            }
        }
    }
}

// ---------------- V transpose + key-interleave: Vb [bh][s][64] -> Vt [bh][e][kappa keys] ----------------
// kappa(p) = (p>>1) + (p&1)*32 within each 64-key tile; matches P packing in attn.
__global__ __launch_bounds__(256) void transpose_v(
    const short* __restrict__ Vb, short* __restrict__ Vt)
{
    __shared__ short T[64 * 66];
    int tid = threadIdx.x;
    int s0 = blockIdx.x * 64, bh = blockIdx.y;
    const short* src = Vb + (size_t)bh * 2048 * 64;
    short* dst = Vt + (size_t)bh * 64 * 2048;

#pragma unroll
    for (int i = 0; i < 2; i++) {
        int slot = i * 256 + tid;
        int s_loc = slot >> 3, ec = slot & 7;
        short8 v = *(const short8*)(src + (size_t)(s0 + s_loc) * 64 + ec * 8);
        *(short8*)(T + s_loc * 66 + ec * 8) = v;
    }
    __syncthreads();
#pragma unroll
    for (int i = 0; i < 2; i++) {
        int slot = i * 256 + tid;
        int e_loc = slot >> 3, sc = slot & 7;
        short8 o;
#pragma unroll
        for (int j = 0; j < 8; j++) {
            int p = sc * 8 + j;
            int kp = (p >> 1) + (p & 1) * 32;   // kappa
            o[j] = T[kp * 66 + e_loc];
        }
        *(short8*)(dst + (size_t)e_loc * 2048 + s0 + sc * 8) = o;
    }
}

// ---------------- flash attention, 32x32x16 MFMA ----------------
// Round-3 chassis: grid (16,48), 256 thr / 4 waves, 32 q-rows/wave, 12 waves/CU.
// K fragments loaded DIRECTLY from global (L1-resident 8KB tile, no Ks LDS).
// V staged in LDS (kappa order); P packed as dwords (kappa order), conflict-free.
__global__ __launch_bounds__(256, 3) void attn(
    const short* __restrict__ Qb, const short* __restrict__ Kb,
    const short* __restrict__ Vt, short* __restrict__ Ctx)
{
    __shared__ short Vs[512 * 8];      // V^T tile: [e 64][64 kappa-ordered keys]
    __shared__ short Ps[4][256 * 8];   // per-wave P: [q 32][64 kappa-ordered keys]
    int tid = threadIdx.x, w = tid >> 6, l = tid & 63;
    int l32 = l & 31, half = l >> 5;
    int qt = blockIdx.x, bh = blockIdx.y;
    const short* Qh  = Qb + (size_t)bh * 2048 * 64;
    const short* Kh  = Kb + (size_t)bh * 2048 * 64;
    const short* Vth = Vt + (size_t)bh * 64 * 2048;
    int qbase = qt * 128 + w * 32;
    short* Psw = &Ps[w][0];

    // V staging: 512 slots over 256 threads, 2 async16 each
    const short* vSrc[2];
    short* vDst[2];
#pragma unroll
    for (int i = 0; i < 2; i++) {
        int slot = i * 256 + tid;
        int row = slot >> 3;
        int g = (slot & 7) ^ (row & 7);
        vSrc[i] = Vth + (size_t)row * 2048 + g * 8;     // + kt*64
        vDst[i] = Vs + (size_t)(i * 256 + w * 64) * 8;  // wave-uniform base
    }

    // Q fragments: 32 q-rows per wave, in registers
    short8 qf[4];
#pragma unroll
    for (int ks = 0; ks < 4; ks++)
        qf[ks] = *(const short8*)(Qh + (size_t)(qbase + l32) * 64 + ks * 16 + half * 8);

    float lsum[16];
#pragma unroll
    for (int r = 0; r < 16; r++) lsum[r] = 0.f;
    floatx16 acc[2] = {};

    for (int kt = 0; kt < 32; kt++) {
        __syncthreads();
#pragma unroll
        for (int i = 0; i < 2; i++)
            async16(vSrc[i] + (size_t)kt * 64, vDst[i]);
        __syncthreads();

        // QK^T with K fragments direct from global (per-nt to bound liveness)
        floatx16 s0 = {}, s1 = {};
        {
            const short* kbase = Kh + (size_t)kt * 64 * 64;
#pragma unroll
            for (int ks = 0; ks < 4; ks++) {
                short8 kf = *(const short8*)(kbase + (size_t)l32 * 64 + ks * 16 + half * 8);
                s0 = __builtin_amdgcn_mfma_f32_32x32x16_bf16(qf[ks], kf, s0, 0, 0, 0);
            }
#pragma unroll
            for (int ks = 0; ks < 4; ks++) {
                short8 kf = *(const short8*)(kbase + (size_t)(32 + l32) * 64 + ks * 16 + half * 8);
                s1 = __builtin_amdgcn_mfma_f32_32x32x16_bf16(qf[ks], kf, s1, 0, 0, 0);
            }
        }

        // exp2 + row-sum + packed kappa P store (dword, conflict-free)
#pragma unroll
        for (int r = 0; r < 16; r++) {
            float p0 = fast_exp2(s0[r]);   // key = l32
            float p1 = fast_exp2(s1[r]);   // key = l32 + 32
            lsum[r] += p0 + p1;
            int q = (r & 3) + 8 * (r >> 2) + 4 * half;
            int slot = q * 8 + ((l32 >> 2) ^ (q & 7));
            *(unsigned*)&Psw[slot * 8 + (l32 & 3) * 2] = pack2bf(p0, p1);
        }

        // PV: A = P (kappa order), B = Vs (kappa order)
        short8 pa[4];
#pragma unroll
        for (int ks = 0; ks < 4; ks++) {
            int chunk = ks * 2 + half;
            pa[ks] = *(const short8*)(Psw + (size_t)(l32 * 8 + (chunk ^ (l32 & 7))) * 8);
        }
#pragma unroll
        for (int nt = 0; nt < 2; nt++) {
#pragma unroll
            for (int ks = 0; ks < 4; ks++) {
                int row = nt * 32 + l32;
                int chunk = ks * 2 + half;
                short8 vf = *(const short8*)(Vs + (size_t)(row * 8 + (chunk ^ (row & 7))) * 8);
                acc[nt] = __builtin_amdgcn_mfma_f32_32x32x16_bf16(pa[ks], vf, acc[nt], 0, 0, 0);
            }
        }
    }

    float inv[16];
#pragma unroll
    for (int r = 0; r < 16; r++) {
        float t = lsum[r];
        t += __shfl_xor(t, 1);
        t += __shfl_xor(t, 2);
        t += __shfl_xor(t, 4);
        t += __shfl_xor(t, 8);
        t += __shfl_xor(t, 16);
        inv[r] = 1.0f / t;
    }
    int b_ = bh / 12, h = bh % 12;
#pragma unroll
    for (int nt = 0; nt < 2; nt++)
#pragma unroll
        for (int r = 0; r < 16; r++) {
            int q = qbase + (r & 3) + 8 * (r >> 2) + 4 * half;
            int e = nt * 32 + l32;
            Ctx[((size_t)(b_ * 2048 + q)) * 768 + h * 64 + e] = f2bf(acc[nt][r] * inv[r]);
        }
}

// ---------------- proj GEMM: out[8192,768] = Ctx @ W2^T + b, fp32 out ----------------
__global__ __launch_bounds__(256) void gemm_out(
    const short* __restrict__ Ctx, const short* __restrict__ W,
    const float* __restrict__ bias, float* __restrict__ out)
{
    __shared__ short As[128 * 32];
    __shared__ short Bs[128 * 32];
    int tid = threadIdx.x;
    int w = tid >> 6, l = tid & 63;
    int lane16 = l & 15, quad = l >> 4;
    int wm = w & 1, wn = w >> 1;
    int m0 = blockIdx.y * 128, n0 = blockIdx.x * 128;

    floatx4 acc[4][4] = {};

    int srow = w * 32 + (l >> 2);
    int scol = (l & 3) * 8;
    const short* Xg = Ctx + (size_t)(m0 + srow) * KDIM + scol;
    const short* Wg = W + (size_t)(n0 + srow) * KDIM + scol;
    short* AsW = As + (w * 32) * 32;
    short* BsW = Bs + (w * 32) * 32;

    for (int kb = 0; kb < KDIM; kb += 32) {
        __syncthreads();
        async16(Xg + kb,             AsW);
        async16(Xg + kb + 16 * KDIM, AsW + 16 * 32);
        async16(Wg + kb,             BsW);
        async16(Wg + kb + 16 * KDIM, BsW + 16 * 32);
        __syncthreads();
        short8 a[4], b[4];
#pragma unroll
        for (int mt = 0; mt < 4; mt++) a[mt] = *(const short8*)(As + (wm * 64 + mt * 16 + lane16) * 32 + quad * 8);
#pragma unroll
        for (int nt = 0; nt < 4; nt++) b[nt] = *(const short8*)(Bs + (wn * 64 + nt * 16 + lane16) * 32 + quad * 8);
#pragma unroll
        for (int mt = 0; mt < 4; mt++)
#pragma unroll
            for (int nt = 0; nt < 4; nt++)
                acc[mt][nt] = __builtin_amdgcn_mfma_f32_16x16x32_bf16(a[mt], b[nt], acc[mt][nt], 0, 0, 0);
    }

#pragma unroll
    for (int mt = 0; mt < 4; mt++) {
        int row = m0 + wm * 64 + mt * 16 + quad * 4;
#pragma unroll
        for (int nt = 0; nt < 4; nt++) {
            int col = n0 + wn * 64 + nt * 16 + lane16;
            float bv = bias[col];
#pragma unroll
            for (int r = 0; r < 4; r++)
                out[(size_t)(row + r) * 768 + col] = acc[mt][nt][r] + bv;
        }
    }
}

extern "C" void kernel_launch(void* const* d_in, const int* in_sizes, int n_in,
                              void* d_out, int out_size, void* d_ws, size_t ws_size,
                              hipStream_t stream) {
    const float* hs     = (const float*)d_in[0];
    const float* qkv_w  = (const float*)d_in[1];
    const float* qkv_b  = (const float*)d_in[2];
    const float* proj_w = (const float*)d_in[3];
    const float* proj_b = (const float*)d_in[4];
    float* out = (float*)d_out;

    short* Xb  = (short*)d_ws;                     // 8192*768 (dead after gemm_qkv; reused as Vt)
    short* W1b = Xb  + (size_t)8192 * 768;         // 2304*768
    short* W2b = W1b + (size_t)2304 * 768;         // 768*768
    short* Qb  = W2b + (size_t)768 * 768;          // 48*2048*64
    short* Kb  = Qb  + (size_t)8192 * 768;
    short* Vb  = Kb  + (size_t)8192 * 768;
    short* Ctx = Vb  + (size_t)8192 * 768;         // 8192*768
    short* Vt  = Xb;                               // [bh][64][2048] kappa-ordered, overlays dead Xb

    int ntot = (N1 + N2 + N3) / 4;
    cvt_all<<<(ntot + 255) / 256, 256, 0, stream>>>(hs, qkv_w, proj_w, Xb, W1b, W2b);

    gemm_qkv<<<dim3(18, 64), 256, 0, stream>>>(Xb, W1b, qkv_b, Qb, Kb, Vb);
    transpose_v<<<dim3(32, 48), 256, 0, stream>>>(Vb, Vt);
    attn<<<dim3(16, 48), 256, 0, stream>>>(Qb, Kb, Vt, Ctx);
    gemm_out<<<dim3(6, 64), 256, 0, stream>>>(Ctx, W2b, proj_b, out);
}

// Round 6
// 221.775 us; speedup vs baseline: 1.2399x; 1.2399x over previous
//
#include <hip/hip_runtime.h>
#include <hip/hip_bf16.h>

using short8   = __attribute__((ext_vector_type(8))) short;
using floatx4  = __attribute__((ext_vector_type(4))) float;
using floatx16 = __attribute__((ext_vector_type(16))) float;

#define KDIM 768
#define QSCALE 0.18033688011112042f   // 0.125 * log2(e)
#define N1 (8192 * 768)
#define N2 (2304 * 768)
#define N3 (768 * 768)

__device__ __forceinline__ short f2bf(float f) {
    union { float f; unsigned u; } v; v.f = f;
    unsigned r = v.u + 0x7fffu + ((v.u >> 16) & 1u);
    return (short)(r >> 16);
}

__device__ __forceinline__ unsigned pack2bf(float a, float b) {
    __hip_bfloat162 h = __float22bfloat162_rn(float2{a, b});
    union { __hip_bfloat162 h; unsigned u; } c; c.h = h;
    return c.u;
}

__device__ __forceinline__ float fast_exp2(float x) {
#if __has_builtin(__builtin_amdgcn_exp2f)
    return __builtin_amdgcn_exp2f(x);
#else
    return exp2f(x);
#endif
}

__device__ __forceinline__ void async16(const void* g, void* l) {
    __builtin_amdgcn_global_load_lds((const __attribute__((address_space(1))) void*)g,
                                     (__attribute__((address_space(3))) void*)l, 16, 0, 0);
}

// ---------------- fused fp32 -> bf16 convert for all three inputs ----------------
__global__ void cvt_all(const float* __restrict__ a, const float* __restrict__ b,
                        const float* __restrict__ c, short* __restrict__ oa,
                        short* __restrict__ ob, short* __restrict__ oc) {
    int i = (blockIdx.x * blockDim.x + threadIdx.x) * 4;
    const float* src; short* dst;
    if (i < N1)            { src = a + i;            dst = oa + i; }
    else if (i < N1 + N2)  { src = b + (i - N1);     dst = ob + (i - N1); }
    else if (i < N1+N2+N3) { src = c + (i - N1 - N2); dst = oc + (i - N1 - N2); }
    else return;
    float4 v = *(const float4*)src;
    short4 o;
    o.x = f2bf(v.x); o.y = f2bf(v.y); o.z = f2bf(v.z); o.w = f2bf(v.w);
    *(short4*)dst = o;
}

// ---------------- QKV GEMM: C[8192,2304] = X @ W^T, scatter to Q/K/V [bh][s][64] ----------------
__global__ __launch_bounds__(256) void gemm_qkv(
    const short* __restrict__ X, const short* __restrict__ W,
    const float* __restrict__ bias,
    short* __restrict__ Qb, short* __restrict__ Kb, short* __restrict__ Vb)
{
    __shared__ short As[128 * 32];
    __shared__ short Bs[128 * 32];
    int tid = threadIdx.x;
    int w = tid >> 6, l = tid & 63;
    int lane16 = l & 15, quad = l >> 4;
    int wm = w & 1, wn = w >> 1;
    int m0 = blockIdx.y * 128, n0 = blockIdx.x * 128;

    floatx4 acc[4][4] = {};

    int srow = w * 32 + (l >> 2);
    int scol = (l & 3) * 8;
    const short* Xg = X + (size_t)(m0 + srow) * KDIM + scol;
    const short* Wg = W + (size_t)(n0 + srow) * KDIM + scol;
    short* AsW = As + (w * 32) * 32;
    short* BsW = Bs + (w * 32) * 32;

    for (int kb = 0; kb < KDIM; kb += 32) {
        __syncthreads();
        async16(Xg + kb,              AsW);
        async16(Xg + kb + 16 * KDIM,  AsW + 16 * 32);
        async16(Wg + kb,              BsW);
        async16(Wg + kb + 16 * KDIM,  BsW + 16 * 32);
        __syncthreads();
        short8 a[4], b[4];
#pragma unroll
        for (int mt = 0; mt < 4; mt++) a[mt] = *(const short8*)(As + (wm * 64 + mt * 16 + lane16) * 32 + quad * 8);
#pragma unroll
        for (int nt = 0; nt < 4; nt++) b[nt] = *(const short8*)(Bs + (wn * 64 + nt * 16 + lane16) * 32 + quad * 8);
#pragma unroll
        for (int mt = 0; mt < 4; mt++)
#pragma unroll
            for (int nt = 0; nt < 4; nt++)
                acc[mt][nt] = __builtin_amdgcn_mfma_f32_16x16x32_bf16(a[mt], b[nt], acc[mt][nt], 0, 0, 0);
    }

#pragma unroll
    for (int mt = 0; mt < 4; mt++) {
        int row = m0 + wm * 64 + mt * 16 + quad * 4;
#pragma unroll
        for (int nt = 0; nt < 4; nt++) {
            int col = n0 + wn * 64 + nt * 16 + lane16;
            int qkv = (col >= 1536) ? 2 : ((col >= 768) ? 1 : 0);
            int rem = col - qkv * 768;
            int h = rem >> 6, e = rem & 63;
            short* dst = (qkv == 0) ? Qb : ((qkv == 1) ? Kb : Vb);
            float sc = (qkv == 0) ? (float)QSCALE : 1.0f;
            float bv = bias[col];
#pragma unroll
            for (int r = 0; r < 4; r++) {
                int i  = row + r;
                int b_ = i >> 11, s_ = i & 2047;
                dst[(((size_t)(b_ * 12 + h)) * 2048 + s_) * 64 + e] = f2bf((acc[mt][nt][r] + bv) * sc);
            }
        }
    }
}

// ---------------- V transpose + sigma key-permute: Vb [bh][s][64] -> Vt [bh][e][64-key tiles] ----------------
// sigma(pos) = pos with bits 2<->3 swapped, within each 64-key tile. This makes the
// in-register P fragments (from transposed QK^T) line up with the V tile's key order.
__global__ __launch_bounds__(256) void transpose_v(
    const short* __restrict__ Vb, short* __restrict__ Vt)
{
    __shared__ short T[64 * 66];
    int tid = threadIdx.x;
    int s0 = blockIdx.x * 64, bh = blockIdx.y;
    const short* src = Vb + (size_t)bh * 2048 * 64;
    short* dst = Vt + (size_t)bh * 64 * 2048;

#pragma unroll
    for (int i = 0; i < 2; i++) {
        int slot = i * 256 + tid;
        int s_loc = slot >> 3, ec = slot & 7;
        short8 v = *(const short8*)(src + (size_t)(s0 + s_loc) * 64 + ec * 8);
        *(short8*)(T + s_loc * 66 + ec * 8) = v;
    }
    __syncthreads();
#pragma unroll
    for (int i = 0; i < 2; i++) {
        int slot = i * 256 + tid;
        int e_loc = slot >> 3, sc = slot & 7;
        short8 o;
#pragma unroll
        for (int j = 0; j < 8; j++) {
            int p = sc * 8 + j;
            int kp = (p & 0x33) | ((p & 4) << 1) | ((p & 8) >> 1);   // sigma: swap bits 2,3
            o[j] = T[kp * 66 + e_loc];
        }
        *(short8*)(dst + (size_t)e_loc * 2048 + s0 + sc * 8) = o;
    }
}

// ---------------- flash attention, 32x32x16 MFMA, transposed QK^T, P in registers ----------------
// grid (16,48), 256 thr / 4 waves, 32 q-rows/wave, 12 waves/CU.
// S^T = MFMA(A=K, B=Q): col = q = l32 -> each lane exits holding its own q-row's P.
// P feeds PV's A operand directly from registers; V tile is sigma-key-permuted to match.
__global__ __launch_bounds__(256, 3) void attn(
    const short* __restrict__ Qb, const short* __restrict__ Kb,
    const short* __restrict__ Vt, short* __restrict__ Ctx)
{
    __shared__ short Ks[512 * 8];      // K tile: [key 64][e 64], natural key order, swizzled slots
    __shared__ short Vs[512 * 8];      // V^T tile: [e 64][64 sigma-ordered keys], swizzled slots
    int tid = threadIdx.x, w = tid >> 6, l = tid & 63;
    int l32 = l & 31, half = l >> 5;
    int qt = blockIdx.x, bh = blockIdx.y;
    const short* Qh  = Qb + (size_t)bh * 2048 * 64;
    const short* Kh  = Kb + (size_t)bh * 2048 * 64;
    const short* Vth = Vt + (size_t)bh * 64 * 2048;
    int qbase = qt * 128 + w * 32;

    // staging: 512 slots each over 256 threads, 2 async16 per thread per tile
    const short* kSrc[2];
    const short* vSrc[2];
    short* kDst[2];
    short* vDst[2];
#pragma unroll
    for (int i = 0; i < 2; i++) {
        int slot = i * 256 + tid;
        int row = slot >> 3;
        int g = (slot & 7) ^ (row & 7);
        kSrc[i] = Kh + (size_t)row * 64 + g * 8;        // + kt*64*64
        vSrc[i] = Vth + (size_t)row * 2048 + g * 8;     // + kt*64
        kDst[i] = Ks + (size_t)(i * 256 + w * 64) * 8;  // wave-uniform base
        vDst[i] = Vs + (size_t)(i * 256 + w * 64) * 8;
    }

    // Q fragments (B operand): lane holds q = qbase + l32, k = e
    short8 qf[4];
#pragma unroll
    for (int ks = 0; ks < 4; ks++)
        qf[ks] = *(const short8*)(Qh + (size_t)(qbase + l32) * 64 + ks * 16 + half * 8);

    float lsum = 0.f;
    floatx16 acc[2] = {};
    int sw = l32 & 7;   // row-swizzle term (row & 7 == l32 & 7 for row = nt*32 + l32)

    for (int kt = 0; kt < 32; kt++) {
        __syncthreads();
#pragma unroll
        for (int i = 0; i < 2; i++) {
            async16(kSrc[i] + (size_t)kt * 64 * 64, kDst[i]);
            async16(vSrc[i] + (size_t)kt * 64,      vDst[i]);
        }
        __syncthreads();

        // S^T: A = K-frag (m = key), B = Q-frag (n = q) -> col = q = l32
        floatx16 s[2];
#pragma unroll
        for (int nt = 0; nt < 2; nt++) {
            floatx16 c = {};
            int rowb = (nt * 32 + l32) * 8;
#pragma unroll
            for (int ks = 0; ks < 4; ks++) {
                short8 kf = *(const short8*)(Ks + (size_t)(rowb + ((ks * 2 + half) ^ sw)) * 8);
                c = __builtin_amdgcn_mfma_f32_32x32x16_bf16(kf, qf[ks], c, 0, 0, 0);
            }
            s[nt] = c;
        }

        // exp2 + row-sum + pack P into A-fragments in registers:
        // reg (nt, r) -> pa[2*nt + (r>>3)], element j = r&7
        union { short8 s8; unsigned u[4]; } pa[4];
#pragma unroll
        for (int nt = 0; nt < 2; nt++)
#pragma unroll
            for (int r = 0; r < 16; r += 2) {
                float p0 = fast_exp2(s[nt][r]);
                float p1 = fast_exp2(s[nt][r + 1]);
                lsum += p0 + p1;
                pa[2 * nt + (r >> 3)].u[(r & 7) >> 1] = pack2bf(p0, p1);
            }

        // PV: A = P (registers), B = V^T tile (sigma key order)
#pragma unroll
        for (int nt = 0; nt < 2; nt++) {
            int rowb = (nt * 32 + l32) * 8;
#pragma unroll
            for (int ks = 0; ks < 4; ks++) {
                short8 vf = *(const short8*)(Vs + (size_t)(rowb + ((ks * 2 + half) ^ sw)) * 8);
                acc[nt] = __builtin_amdgcn_mfma_f32_32x32x16_bf16(pa[ks].s8, vf, acc[nt], 0, 0, 0);
            }
        }
    }

    // denominator for q = l32 (this lane's own q-row): combine the two halves
    float denom = lsum + __shfl_xor(lsum, 32);
    float inv_self = 1.0f / denom;

    int b_ = bh / 12, h = bh % 12;
#pragma unroll
    for (int nt = 0; nt < 2; nt++)
#pragma unroll
        for (int r = 0; r < 16; r++) {
            int qloc = (r & 3) + 8 * (r >> 2) + 4 * half;
            float invq = __shfl(inv_self, qloc);   // lane qloc holds q=qloc's inverse denom
            int q = qbase + qloc;
            int e = nt * 32 + l32;
            Ctx[((size_t)(b_ * 2048 + q)) * 768 + h * 64 + e] = f2bf(acc[nt][r] * invq);
        }
}

// ---------------- proj GEMM: out[8192,768] = Ctx @ W2^T + b, fp32 out ----------------
__global__ __launch_bounds__(256) void gemm_out(
    const short* __restrict__ Ctx, const short* __restrict__ W,
    const float* __restrict__ bias, float* __restrict__ out)
{
    __shared__ short As[128 * 32];
    __shared__ short Bs[128 * 32];
    int tid = threadIdx.x;
    int w = tid >> 6, l = tid & 63;
    int lane16 = l & 15, quad = l >> 4;
    int wm = w & 1, wn = w >> 1;
    int m0 = blockIdx.y * 128, n0 = blockIdx.x * 128;

    floatx4 acc[4][4] = {};

    int srow = w * 32 + (l >> 2);
    int scol = (l & 3) * 8;
    const short* Xg = Ctx + (size_t)(m0 + srow) * KDIM + scol;
    const short* Wg = W + (size_t)(n0 + srow) * KDIM + scol;
    short* AsW = As + (w * 32) * 32;
    short* BsW = Bs + (w * 32) * 32;

    for (int kb = 0; kb < KDIM; kb += 32) {
        __syncthreads();
        async16(Xg + kb,             AsW);
        async16(Xg + kb + 16 * KDIM, AsW + 16 * 32);
        async16(Wg + kb,             BsW);
        async16(Wg + kb + 16 * KDIM, BsW + 16 * 32);
        __syncthreads();
        short8 a[4], b[4];
#pragma unroll
        for (int mt = 0; mt < 4; mt++) a[mt] = *(const short8*)(As + (wm * 64 + mt * 16 + lane16) * 32 + quad * 8);
#pragma unroll
        for (int nt = 0; nt < 4; nt++) b[nt] = *(const short8*)(Bs + (wn * 64 + nt * 16 + lane16) * 32 + quad * 8);
#pragma unroll
        for (int mt = 0; mt < 4; mt++)
#pragma unroll
            for (int nt = 0; nt < 4; nt++)
                acc[mt][nt] = __builtin_amdgcn_mfma_f32_16x16x32_bf16(a[mt], b[nt], acc[mt][nt], 0, 0, 0);
    }

#pragma unroll
    for (int mt = 0; mt < 4; mt++) {
        int row = m0 + wm * 64 + mt * 16 + quad * 4;
#pragma unroll
        for (int nt = 0; nt < 4; nt++) {
            int col = n0 + wn * 64 + nt * 16 + lane16;
            float bv = bias[col];
#pragma unroll
            for (int r = 0; r < 4; r++)
                out[(size_t)(row + r) * 768 + col] = acc[mt][nt][r] + bv;
        }
    }
}

extern "C" void kernel_launch(void* const* d_in, const int* in_sizes, int n_in,
                              void* d_out, int out_size, void* d_ws, size_t ws_size,
                              hipStream_t stream) {
    const float* hs     = (const float*)d_in[0];
    const float* qkv_w  = (const float*)d_in[1];
    const float* qkv_b  = (const float*)d_in[2];
    const float* proj_w = (const float*)d_in[3];
    const float* proj_b = (const float*)d_in[4];
    float* out = (float*)d_out;

    short* Xb  = (short*)d_ws;                     // 8192*768 (dead after gemm_qkv; reused as Vt)
    short* W1b = Xb  + (size_t)8192 * 768;         // 2304*768
    short* W2b = W1b + (size_t)2304 * 768;         // 768*768
    short* Qb  = W2b + (size_t)768 * 768;          // 48*2048*64
    short* Kb  = Qb  + (size_t)8192 * 768;
    short* Vb  = Kb  + (size_t)8192 * 768;
    short* Ctx = Vb  + (size_t)8192 * 768;         // 8192*768
    short* Vt  = Xb;                               // [bh][64][2048] sigma-ordered, overlays dead Xb

    int ntot = (N1 + N2 + N3) / 4;
    cvt_all<<<(ntot + 255) / 256, 256, 0, stream>>>(hs, qkv_w, proj_w, Xb, W1b, W2b);

    gemm_qkv<<<dim3(18, 64), 256, 0, stream>>>(Xb, W1b, qkv_b, Qb, Kb, Vb);
    transpose_v<<<dim3(32, 48), 256, 0, stream>>>(Vb, Vt);
    attn<<<dim3(16, 48), 256, 0, stream>>>(Qb, Kb, Vt, Ctx);
    gemm_out<<<dim3(6, 64), 256, 0, stream>>>(Ctx, W2b, proj_b, out);
}